// Round 3
// baseline (148.157 us; speedup 1.0000x reference)
//
#include <hip/hip_runtime.h>

#define NEG_SLOPE 0.2f
#define BCAP 8192  // per-bucket slot capacity (mean 4096, sigma ~64 -> +64 sigma)

typedef __attribute__((ext_vector_type(8))) short short8;
typedef __attribute__((ext_vector_type(4))) float floatx4;

__device__ __forceinline__ unsigned f2bf(float x) {
  unsigned u = __float_as_uint(x);
  unsigned r = ((u >> 16) & 1u) + 0x7fffu;
  return (u + r) >> 16;
}
__device__ __forceinline__ float bf2f(unsigned hi16) {
  return __uint_as_float(hi16 << 16);
}

// ---------------- one-shot: W -> MFMA B-fragments (hi/lo) + zero bucket cursors ----------------
__global__ __launch_bounds__(256) void k_prep(const float* __restrict__ W,
                                              uint4* __restrict__ gWf,
                                              int* __restrict__ bcur, int NB2) {
  if (blockIdx.x == 0 && threadIdx.x < NB2) bcur[threadIdx.x] = 0;
  const int u = blockIdx.x * 256 + threadIdx.x;
  if (u >= 2048) return;
  int ln = u & 63;
  int kc = (u >> 6) & 3;
  int ct = u >> 8;
  int n = ct * 16 + (ln & 15);
  int kb = kc * 32 + (ln >> 4) * 8;
  int head = n >> 5;
  const float* src = W + head * 4096 + (size_t)kb * 32 + (n & 31);
  unsigned hi[4], lo[4];
#pragma unroll
  for (int jj = 0; jj < 4; ++jj) {
    float w0 = src[(2 * jj) * 32];
    float w1 = src[(2 * jj + 1) * 32];
    unsigned h0 = f2bf(w0), h1 = f2bf(w1);
    unsigned l0 = f2bf(w0 - bf2f(h0)), l1 = f2bf(w1 - bf2f(h1));
    hi[jj] = h0 | (h1 << 16);
    lo[jj] = l0 | (l1 << 16);
  }
  gWf[u] = make_uint4(hi[0], hi[1], hi[2], hi[3]);
  gWf[2048 + u] = make_uint4(lo[0], lo[1], lo[2], lo[3]);
}

// ---------------- fused: edge binning + MFMA projection GEMM + attention dots ----------------
// LDS cut 64->38 KB (Bh stays in LDS; Bl read straight from L2-resident gWf):
// 4 blocks/CU instead of 2 -> binning prologue overlaps neighbors' MFMA work.
__global__ __launch_bounds__(256) void k_gemm(const float* __restrict__ h,
                                              const uint4* __restrict__ gWf,
                                              const float* __restrict__ a,
                                              const int* __restrict__ ei,
                                              int* __restrict__ bcur,
                                              uint2* __restrict__ gpairs,
                                              unsigned short* __restrict__ hp16,
                                              float* __restrict__ ssrc,
                                              float* __restrict__ sdst,
                                              int N, int E, int NB1, int NB2) {
  __shared__ unsigned lds_u[9728];  // 38 KB multi-use: bin scratch -> Bh frags -> epilogue
  const int tid = threadIdx.x;

  if (blockIdx.x < NB1) {  // block-uniform branch: barriers inside are legal
    uint2* stage = (uint2*)lds_u;              // 4096 pairs = 32 KB
    int* cnt = (int*)&lds_u[8192];
    int* start = (int*)&lds_u[8448];
    int* cur = (int*)&lds_u[8704];
    int* gbase = (int*)&lds_u[8960];
    int* scn = (int*)&lds_u[9216];
    const int e0 = blockIdx.x * 4096;
    for (int i = tid; i < NB2; i += 256) cnt[i] = 0;
    __syncthreads();
    int sarr[16], darr[16];
#pragma unroll
    for (int j = 0; j < 16; ++j) {
      int e = e0 + j * 256 + tid;
      if (e < E) {
        sarr[j] = ei[e];
        darr[j] = ei[E + e];
        atomicAdd(&cnt[darr[j] >> 8], 1);
      } else {
        darr[j] = -1;
      }
    }
    __syncthreads();
    int s = (tid < NB2) ? cnt[tid] : 0;
    scn[tid] = s;
    __syncthreads();
    for (int off = 1; off < 256; off <<= 1) {
      int t = (tid >= off) ? scn[tid - off] : 0;
      __syncthreads();
      scn[tid] += t;
      __syncthreads();
    }
    if (tid < NB2) {
      start[tid] = scn[tid] - s;
      cur[tid] = scn[tid] - s;
      gbase[tid] = s ? atomicAdd(&bcur[tid], s) : 0;  // reserve run in bucket
    }
    __syncthreads();
#pragma unroll
    for (int j = 0; j < 16; ++j) {
      if (darr[j] >= 0) {
        int b = darr[j] >> 8;
        int pos = atomicAdd(&cur[b], 1);
        stage[pos] = make_uint2((unsigned)sarr[j], (unsigned)darr[j]);
      }
    }
    __syncthreads();
    const int total = start[NB2 - 1] + cnt[NB2 - 1];
    for (int u = tid; u < total; u += 256) {
      uint2 pr = stage[u];
      int b = (int)(pr.y >> 8);
      gpairs[(size_t)b * BCAP + gbase[b] + (u - start[b])] = pr;
    }
    __syncthreads();  // lds_u scratch free
  }

  const int lane = tid & 63;
  const int wv = tid >> 6;
  const int quad = lane >> 4;
  const int l16 = lane & 15;

  // stage Bh fragments only (32 KB); Bl comes from global (L2-resident, coalesced)
  for (int u = tid; u < 2048; u += 256)
    *(uint4*)&lds_u[u * 4] = gWf[u];

  const int row0 = blockIdx.x * 64;
  const int r = row0 + wv * 16 + l16;
  short8 Ah[4], Al[4];
#pragma unroll
  for (int kc = 0; kc < 4; ++kc) {
    float v[8];
    if (r < N) {
      float4 fa = *(const float4*)&h[(size_t)r * 128 + kc * 32 + quad * 8];
      float4 fb = *(const float4*)&h[(size_t)r * 128 + kc * 32 + quad * 8 + 4];
      v[0] = fa.x; v[1] = fa.y; v[2] = fa.z; v[3] = fa.w;
      v[4] = fb.x; v[5] = fb.y; v[6] = fb.z; v[7] = fb.w;
    } else {
#pragma unroll
      for (int j = 0; j < 8; ++j) v[j] = 0.f;
    }
#pragma unroll
    for (int j = 0; j < 8; ++j) {
      unsigned hi = f2bf(v[j]);
      Ah[kc][j] = (short)hi;
      Al[kc][j] = (short)f2bf(v[j] - bf2f(hi));
    }
  }
  __syncthreads();

  floatx4 C[8];
#pragma unroll
  for (int ct = 0; ct < 8; ++ct) {
    floatx4 c = {0.f, 0.f, 0.f, 0.f};
#pragma unroll
    for (int kc = 0; kc < 4; ++kc) {
      int bidx = (ct * 4 + kc) * 64 + lane;
      short8 Bh, Bl;
      *(uint4*)&Bh = *(const uint4*)&lds_u[bidx * 4];
      *(uint4*)&Bl = gWf[2048 + bidx];
      c = __builtin_amdgcn_mfma_f32_16x16x32_bf16(Ah[kc], Bh, c, 0, 0, 0);
      c = __builtin_amdgcn_mfma_f32_16x16x32_bf16(Al[kc], Bh, c, 0, 0, 0);
      c = __builtin_amdgcn_mfma_f32_16x16x32_bf16(Ah[kc], Bl, c, 0, 0, 0);
    }
    C[ct] = c;
  }
  __syncthreads();

  float* epi = (float*)lds_u;
#pragma unroll
  for (int ct = 0; ct < 8; ++ct) {
#pragma unroll
    for (int reg = 0; reg < 4; ++reg) {
      int rr = wv * 16 + quad * 4 + reg;
      epi[rr * 132 + ct * 16 + l16] = C[ct][reg];
    }
  }
  __syncthreads();

  const int row_l = tid >> 2;
  const int hh = tid & 3;
  const int rg = row0 + row_l;
  if (rg < N) {
    const float* rowp = &epi[row_l * 132 + hh * 32];
    float ss = 0.f, sd = 0.f;
    unsigned pka[16];
#pragma unroll
    for (int e = 0; e < 8; ++e) {
      float4 c4 = *(const float4*)&rowp[e * 4];
      float4 as = *(const float4*)&a[hh * 64 + e * 4];
      float4 ad = *(const float4*)&a[hh * 64 + 32 + e * 4];
      ss += c4.x * as.x + c4.y * as.y + c4.z * as.z + c4.w * as.w;
      sd += c4.x * ad.x + c4.y * ad.y + c4.z * ad.z + c4.w * ad.w;
      pka[e * 2] = f2bf(c4.x) | (f2bf(c4.y) << 16);
      pka[e * 2 + 1] = f2bf(c4.z) | (f2bf(c4.w) << 16);
    }
    unsigned short* dst = &hp16[(size_t)rg * 128 + hh * 32];
    *(uint4*)(dst) = make_uint4(pka[0], pka[1], pka[2], pka[3]);
    *(uint4*)(dst + 8) = make_uint4(pka[4], pka[5], pka[6], pka[7]);
    *(uint4*)(dst + 16) = make_uint4(pka[8], pka[9], pka[10], pka[11]);
    *(uint4*)(dst + 24) = make_uint4(pka[12], pka[13], pka[14], pka[15]);
    ssrc[(size_t)rg * 4 + hh] = ss;
    sdst[(size_t)rg * 4 + hh] = sd;
  }
}

// ---------------- fused per-bucket counting sort (LDS-resident) + aggregation ----------------
// SPLIT=2: two blocks per bucket, each filters the bucket's pairs to its
// 128-dst half. Grid 196 -> 392 (machine fill 38% -> 77%). Weights recomputed
// inline from L2-resident ssrc + LDS-preloaded sdst; no extra global arrays.
__global__ __launch_bounds__(1024) void k_sortagg(const int* __restrict__ bcur,
                                                  const uint2* __restrict__ gpairs,
                                                  const float* __restrict__ ssrc,
                                                  const float* __restrict__ sdst,
                                                  const uint4* __restrict__ hp4,
                                                  float* __restrict__ out, int N) {
  __shared__ int cnt2[128], start2[128], cur2[128], lds[128];
  __shared__ int srcsort[4096];   // 16 KB (sub-bucket mean 2048, +45 sigma)
  __shared__ float sdl[512];      // sdst[4] for this half-bucket's 128 dsts
  const int tid = threadIdx.x;
  const int b = blockIdx.x >> 1;          // bucket
  const int half = blockIdx.x & 1;        // which 128-dst half
  const size_t base = (size_t)b * BCAP;
  const int size = min(bcur[b], BCAP);    // defensive clamp
  const int d0s = (b << 8) + half * 128;  // sub-range base
  const int ndst = min(128, N - d0s);     // may be <=0 for tail half

  if (tid < 128) cnt2[tid] = 0;
  for (int i = tid; i < ndst * 4; i += 1024) sdl[i] = sdst[(size_t)d0s * 4 + i];
  __syncthreads();

  // stage bucket pairs in registers, filter to this half (BCAP = 8 * 1024)
  uint2 pr[8];
  int rel[8];
#pragma unroll
  for (int j = 0; j < 8; ++j) {
    const int u = tid + j * 1024;
    if (u < size) pr[j] = gpairs[base + u];
    else pr[j].y = 0xffffffffu;
    rel[j] = (int)pr[j].y - d0s;
    if ((unsigned)rel[j] >= 128u) rel[j] = -1;
  }
#pragma unroll
  for (int j = 0; j < 8; ++j)
    if (rel[j] >= 0) atomicAdd(&cnt2[rel[j]], 1);
  __syncthreads();

  // prefix scan over 128 counters (barriers uniform across the 1024 threads)
  if (tid < 128) lds[tid] = cnt2[tid];
  __syncthreads();
  for (int off = 1; off < 128; off <<= 1) {
    const int t = (tid < 128 && tid >= off) ? lds[tid - off] : 0;
    __syncthreads();
    if (tid < 128) lds[tid] += t;
    __syncthreads();
  }
  if (tid < 128) {
    start2[tid] = lds[tid] - cnt2[tid];
    cur2[tid] = lds[tid] - cnt2[tid];
  }
  __syncthreads();

  // scatter src ids into sorted LDS positions
#pragma unroll
  for (int j = 0; j < 8; ++j) {
    if (rel[j] >= 0) {
      const int pos = atomicAdd(&cur2[rel[j]], 1);
      srcsort[pos] = (int)pr[j].x;
    }
  }
  __syncthreads();

  // aggregation: 16 lanes per dst, 64 dsts in flight, <=2 rounds
  const int l = tid & 15;
  const int hh = l >> 2;
  for (int dl = tid >> 4; dl < ndst; dl += 64) {
    const int d = d0s + dl;
    const int beg = start2[dl];
    const int end = beg + cnt2[dl];
    const float sdv = sdl[dl * 4 + hh];

    float den[4] = {0.f, 0.f, 0.f, 0.f};
    float acc[8];
#pragma unroll
    for (int j = 0; j < 8; ++j) acc[j] = 0.f;

    int p = beg;
    for (; p + 3 < end; p += 4) {
      int s[4];
      float w[4];
      uint4 v[4];
#pragma unroll
      for (int q = 0; q < 4; ++q) s[q] = srcsort[p + q];
#pragma unroll
      for (int q = 0; q < 4; ++q) {
        float x = ssrc[(size_t)s[q] * 4 + hh] + sdv;
        x = x >= 0.f ? x : NEG_SLOPE * x;
        w[q] = __expf(x);
        v[q] = hp4[(size_t)s[q] * 16 + l];
      }
#pragma unroll
      for (int q = 0; q < 4; ++q) {
        den[q] += w[q];
        acc[0] = fmaf(w[q], bf2f(v[q].x & 0xffffu), acc[0]);
        acc[1] = fmaf(w[q], bf2f(v[q].x >> 16), acc[1]);
        acc[2] = fmaf(w[q], bf2f(v[q].y & 0xffffu), acc[2]);
        acc[3] = fmaf(w[q], bf2f(v[q].y >> 16), acc[3]);
        acc[4] = fmaf(w[q], bf2f(v[q].z & 0xffffu), acc[4]);
        acc[5] = fmaf(w[q], bf2f(v[q].z >> 16), acc[5]);
        acc[6] = fmaf(w[q], bf2f(v[q].w & 0xffffu), acc[6]);
        acc[7] = fmaf(w[q], bf2f(v[q].w >> 16), acc[7]);
      }
    }
    for (; p < end; ++p) {
      const int s0 = srcsort[p];
      float x = ssrc[(size_t)s0 * 4 + hh] + sdv;
      x = x >= 0.f ? x : NEG_SLOPE * x;
      const float w0 = __expf(x);
      const uint4 v0 = hp4[(size_t)s0 * 16 + l];
      den[0] += w0;
      acc[0] = fmaf(w0, bf2f(v0.x & 0xffffu), acc[0]);
      acc[1] = fmaf(w0, bf2f(v0.x >> 16), acc[1]);
      acc[2] = fmaf(w0, bf2f(v0.y & 0xffffu), acc[2]);
      acc[3] = fmaf(w0, bf2f(v0.y >> 16), acc[3]);
      acc[4] = fmaf(w0, bf2f(v0.z & 0xffffu), acc[4]);
      acc[5] = fmaf(w0, bf2f(v0.z >> 16), acc[5]);
      acc[6] = fmaf(w0, bf2f(v0.w & 0xffffu), acc[6]);
      acc[7] = fmaf(w0, bf2f(v0.w >> 16), acc[7]);
    }
    const float rden = 1.f / fmaxf((den[0] + den[1]) + (den[2] + den[3]), 1e-16f);
    float o[8];
#pragma unroll
    for (int j = 0; j < 8; ++j) {
      const float x = acc[j] * rden;
      o[j] = x > 0.f ? x : expm1f(x);
    }
    float* dst = &out[(size_t)d * 128 + l * 8];
    *(float4*)dst = make_float4(o[0], o[1], o[2], o[3]);
    *(float4*)(dst + 4) = make_float4(o[4], o[5], o[6], o[7]);
  }
}

extern "C" void kernel_launch(void* const* d_in, const int* in_sizes, int n_in,
                              void* d_out, int out_size, void* d_ws, size_t ws_size,
                              hipStream_t stream) {
  const float* h = (const float*)d_in[0];
  const int* ei = (const int*)d_in[1];
  const float* W = (const float*)d_in[2];
  const float* a = (const float*)d_in[3];
  float* out = (float*)d_out;
  const int N = in_sizes[0] / 128;
  const int E = in_sizes[1] / 2;
  const int NB2 = (N + 255) >> 8;          // coarse buckets (dst>>8), <=256
  const int NB1 = (E + 4095) / 4096;       // edge chunks
  const int NBG = max((N + 63) / 64, NB1); // fused gemm+bin grid

  char* ws = (char*)d_ws;
  uint4* gWf = (uint4*)ws;                                   // 4096 (64 KB)
  unsigned short* hp16 = (unsigned short*)(gWf + 4096);      // N*128 bf16
  uint2* gpairs = (uint2*)(hp16 + (size_t)N * 128);          // NB2*BCAP padded pairs
  float* ssrc = (float*)(gpairs + (size_t)NB2 * BCAP);       // N*4
  float* sdst = ssrc + (size_t)N * 4;                        // N*4
  int* bcur = (int*)(sdst + (size_t)N * 4);                  // NB2

  k_prep<<<8, 256, 0, stream>>>(W, gWf, bcur, NB2);
  k_gemm<<<NBG, 256, 0, stream>>>(h, gWf, a, ei, bcur, gpairs, hp16, ssrc, sdst,
                                  N, E, NB1, NB2);
  k_sortagg<<<NB2 * 2, 1024, 0, stream>>>(bcur, gpairs, ssrc, sdst,
                                          (const uint4*)hp16, out, N);
}

// Round 4
// 142.922 us; speedup vs baseline: 1.0366x; 1.0366x over previous
//
#include <hip/hip_runtime.h>

#define NEG_SLOPE 0.2f
#define BCAP 8192  // per-bucket slot capacity (mean 4096, sigma ~64 -> +64 sigma)

typedef __attribute__((ext_vector_type(8))) short short8;
typedef __attribute__((ext_vector_type(4))) float floatx4;

__device__ __forceinline__ unsigned f2bf(float x) {
  unsigned u = __float_as_uint(x);
  unsigned r = ((u >> 16) & 1u) + 0x7fffu;
  return (u + r) >> 16;
}
__device__ __forceinline__ float bf2f(unsigned hi16) {
  return __uint_as_float(hi16 << 16);
}

// ---------------- one-shot: W -> MFMA B-fragments (hi/lo) + zero bucket cursors ----------------
__global__ __launch_bounds__(256) void k_prep(const float* __restrict__ W,
                                              uint4* __restrict__ gWf,
                                              int* __restrict__ bcur, int NB2) {
  if (blockIdx.x == 0 && threadIdx.x < NB2) bcur[threadIdx.x] = 0;
  const int u = blockIdx.x * 256 + threadIdx.x;
  if (u >= 2048) return;
  int ln = u & 63;
  int kc = (u >> 6) & 3;
  int ct = u >> 8;
  int n = ct * 16 + (ln & 15);
  int kb = kc * 32 + (ln >> 4) * 8;
  int head = n >> 5;
  const float* src = W + head * 4096 + (size_t)kb * 32 + (n & 31);
  unsigned hi[4], lo[4];
#pragma unroll
  for (int jj = 0; jj < 4; ++jj) {
    float w0 = src[(2 * jj) * 32];
    float w1 = src[(2 * jj + 1) * 32];
    unsigned h0 = f2bf(w0), h1 = f2bf(w1);
    unsigned l0 = f2bf(w0 - bf2f(h0)), l1 = f2bf(w1 - bf2f(h1));
    hi[jj] = h0 | (h1 << 16);
    lo[jj] = l0 | (l1 << 16);
  }
  gWf[u] = make_uint4(hi[0], hi[1], hi[2], hi[3]);
  gWf[2048 + u] = make_uint4(lo[0], lo[1], lo[2], lo[3]);
}

// ---------------- fused: edge binning + MFMA projection GEMM + attention dots ----------------
// Round-2 form: Bh AND Bl staged in 64 KB LDS; all inner-loop reads are
// ds_read_b128 (no global loads on the MFMA critical path).
__global__ __launch_bounds__(256) void k_gemm(const float* __restrict__ h,
                                              const uint4* __restrict__ gWf,
                                              const float* __restrict__ a,
                                              const int* __restrict__ ei,
                                              int* __restrict__ bcur,
                                              uint2* __restrict__ gpairs,
                                              unsigned short* __restrict__ hp16,
                                              float* __restrict__ ssrc,
                                              float* __restrict__ sdst,
                                              int N, int E, int NB1, int NB2) {
  __shared__ unsigned lds_u[16384];  // 64 KB multi-use: bin scratch -> B-frags -> epilogue
  const int tid = threadIdx.x;

  if (blockIdx.x < NB1) {  // block-uniform branch: barriers inside are legal
    uint2* stage = (uint2*)lds_u;              // 4096 pairs = 32 KB
    int* cnt = (int*)&lds_u[8192];
    int* start = (int*)&lds_u[8448];
    int* cur = (int*)&lds_u[8704];
    int* gbase = (int*)&lds_u[8960];
    int* scn = (int*)&lds_u[9216];
    const int e0 = blockIdx.x * 4096;
    for (int i = tid; i < NB2; i += 256) cnt[i] = 0;
    __syncthreads();
    int sarr[16], darr[16];
#pragma unroll
    for (int j = 0; j < 16; ++j) {
      int e = e0 + j * 256 + tid;
      if (e < E) {
        sarr[j] = ei[e];
        darr[j] = ei[E + e];
        atomicAdd(&cnt[darr[j] >> 8], 1);
      } else {
        darr[j] = -1;
      }
    }
    __syncthreads();
    int s = (tid < NB2) ? cnt[tid] : 0;
    scn[tid] = s;
    __syncthreads();
    for (int off = 1; off < 256; off <<= 1) {
      int t = (tid >= off) ? scn[tid - off] : 0;
      __syncthreads();
      scn[tid] += t;
      __syncthreads();
    }
    if (tid < NB2) {
      start[tid] = scn[tid] - s;
      cur[tid] = scn[tid] - s;
      gbase[tid] = s ? atomicAdd(&bcur[tid], s) : 0;  // reserve run in bucket
    }
    __syncthreads();
#pragma unroll
    for (int j = 0; j < 16; ++j) {
      if (darr[j] >= 0) {
        int b = darr[j] >> 8;
        int pos = atomicAdd(&cur[b], 1);
        stage[pos] = make_uint2((unsigned)sarr[j], (unsigned)darr[j]);
      }
    }
    __syncthreads();
    const int total = start[NB2 - 1] + cnt[NB2 - 1];
    for (int u = tid; u < total; u += 256) {
      uint2 pr = stage[u];
      int b = (int)(pr.y >> 8);
      gpairs[(size_t)b * BCAP + gbase[b] + (u - start[b])] = pr;
    }
    __syncthreads();  // lds_u scratch free
  }

  const int lane = tid & 63;
  const int wv = tid >> 6;
  const int quad = lane >> 4;
  const int l16 = lane & 15;

  for (int u = tid; u < 4096; u += 256)
    *(uint4*)&lds_u[u * 4] = gWf[u];

  const int row0 = blockIdx.x * 64;
  const int r = row0 + wv * 16 + l16;
  short8 Ah[4], Al[4];
#pragma unroll
  for (int kc = 0; kc < 4; ++kc) {
    float v[8];
    if (r < N) {
      float4 fa = *(const float4*)&h[(size_t)r * 128 + kc * 32 + quad * 8];
      float4 fb = *(const float4*)&h[(size_t)r * 128 + kc * 32 + quad * 8 + 4];
      v[0] = fa.x; v[1] = fa.y; v[2] = fa.z; v[3] = fa.w;
      v[4] = fb.x; v[5] = fb.y; v[6] = fb.z; v[7] = fb.w;
    } else {
#pragma unroll
      for (int j = 0; j < 8; ++j) v[j] = 0.f;
    }
#pragma unroll
    for (int j = 0; j < 8; ++j) {
      unsigned hi = f2bf(v[j]);
      Ah[kc][j] = (short)hi;
      Al[kc][j] = (short)f2bf(v[j] - bf2f(hi));
    }
  }
  __syncthreads();

  floatx4 C[8];
#pragma unroll
  for (int ct = 0; ct < 8; ++ct) {
    floatx4 c = {0.f, 0.f, 0.f, 0.f};
#pragma unroll
    for (int kc = 0; kc < 4; ++kc) {
      int bidx = ((ct * 4 + kc) * 64 + lane) * 4;
      short8 Bh, Bl;
      *(uint4*)&Bh = *(const uint4*)&lds_u[bidx];
      *(uint4*)&Bl = *(const uint4*)&lds_u[8192 + bidx];
      c = __builtin_amdgcn_mfma_f32_16x16x32_bf16(Ah[kc], Bh, c, 0, 0, 0);
      c = __builtin_amdgcn_mfma_f32_16x16x32_bf16(Al[kc], Bh, c, 0, 0, 0);
      c = __builtin_amdgcn_mfma_f32_16x16x32_bf16(Ah[kc], Bl, c, 0, 0, 0);
    }
    C[ct] = c;
  }
  __syncthreads();

  float* epi = (float*)lds_u;
#pragma unroll
  for (int ct = 0; ct < 8; ++ct) {
#pragma unroll
    for (int reg = 0; reg < 4; ++reg) {
      int rr = wv * 16 + quad * 4 + reg;
      epi[rr * 132 + ct * 16 + l16] = C[ct][reg];
    }
  }
  __syncthreads();

  const int row_l = tid >> 2;
  const int hh = tid & 3;
  const int rg = row0 + row_l;
  if (rg < N) {
    const float* rowp = &epi[row_l * 132 + hh * 32];
    float ss = 0.f, sd = 0.f;
    unsigned pka[16];
#pragma unroll
    for (int e = 0; e < 8; ++e) {
      float4 c4 = *(const float4*)&rowp[e * 4];
      float4 as = *(const float4*)&a[hh * 64 + e * 4];
      float4 ad = *(const float4*)&a[hh * 64 + 32 + e * 4];
      ss += c4.x * as.x + c4.y * as.y + c4.z * as.z + c4.w * as.w;
      sd += c4.x * ad.x + c4.y * ad.y + c4.z * ad.z + c4.w * ad.w;
      pka[e * 2] = f2bf(c4.x) | (f2bf(c4.y) << 16);
      pka[e * 2 + 1] = f2bf(c4.z) | (f2bf(c4.w) << 16);
    }
    unsigned short* dst = &hp16[(size_t)rg * 128 + hh * 32];
    *(uint4*)(dst) = make_uint4(pka[0], pka[1], pka[2], pka[3]);
    *(uint4*)(dst + 8) = make_uint4(pka[4], pka[5], pka[6], pka[7]);
    *(uint4*)(dst + 16) = make_uint4(pka[8], pka[9], pka[10], pka[11]);
    *(uint4*)(dst + 24) = make_uint4(pka[12], pka[13], pka[14], pka[15]);
    ssrc[(size_t)rg * 4 + hh] = ss;
    sdst[(size_t)rg * 4 + hh] = sd;
  }
}

// ---------------- fused per-bucket counting sort (LDS-resident) + aggregation ----------------
// SPLIT=2: two blocks per bucket, each filters the bucket's pairs to its
// 128-dst half. Grid 196 -> 392 (machine fill 38% -> 77%). Weights recomputed
// inline from L2-resident ssrc + LDS-preloaded sdst; no extra global arrays.
__global__ __launch_bounds__(1024) void k_sortagg(const int* __restrict__ bcur,
                                                  const uint2* __restrict__ gpairs,
                                                  const float* __restrict__ ssrc,
                                                  const float* __restrict__ sdst,
                                                  const uint4* __restrict__ hp4,
                                                  float* __restrict__ out, int N) {
  __shared__ int cnt2[128], start2[128], cur2[128], lds[128];
  __shared__ int srcsort[4096];   // 16 KB (sub-bucket mean 2048, +45 sigma)
  __shared__ float sdl[512];      // sdst[4] for this half-bucket's 128 dsts
  const int tid = threadIdx.x;
  const int b = blockIdx.x >> 1;          // bucket
  const int half = blockIdx.x & 1;        // which 128-dst half
  const size_t base = (size_t)b * BCAP;
  const int size = min(bcur[b], BCAP);    // defensive clamp
  const int d0s = (b << 8) + half * 128;  // sub-range base
  const int ndst = min(128, N - d0s);     // may be <=0 for tail half

  if (tid < 128) cnt2[tid] = 0;
  for (int i = tid; i < ndst * 4; i += 1024) sdl[i] = sdst[(size_t)d0s * 4 + i];
  __syncthreads();

  // stage bucket pairs in registers, filter to this half (BCAP = 8 * 1024)
  uint2 pr[8];
  int rel[8];
#pragma unroll
  for (int j = 0; j < 8; ++j) {
    const int u = tid + j * 1024;
    if (u < size) pr[j] = gpairs[base + u];
    else pr[j].y = 0xffffffffu;
    rel[j] = (int)pr[j].y - d0s;
    if ((unsigned)rel[j] >= 128u) rel[j] = -1;
  }
#pragma unroll
  for (int j = 0; j < 8; ++j)
    if (rel[j] >= 0) atomicAdd(&cnt2[rel[j]], 1);
  __syncthreads();

  // prefix scan over 128 counters (barriers uniform across the 1024 threads)
  if (tid < 128) lds[tid] = cnt2[tid];
  __syncthreads();
  for (int off = 1; off < 128; off <<= 1) {
    const int t = (tid < 128 && tid >= off) ? lds[tid - off] : 0;
    __syncthreads();
    if (tid < 128) lds[tid] += t;
    __syncthreads();
  }
  if (tid < 128) {
    start2[tid] = lds[tid] - cnt2[tid];
    cur2[tid] = lds[tid] - cnt2[tid];
  }
  __syncthreads();

  // scatter src ids into sorted LDS positions
#pragma unroll
  for (int j = 0; j < 8; ++j) {
    if (rel[j] >= 0) {
      const int pos = atomicAdd(&cur2[rel[j]], 1);
      srcsort[pos] = (int)pr[j].x;
    }
  }
  __syncthreads();

  // aggregation: 16 lanes per dst, 64 dsts in flight, <=2 rounds
  const int l = tid & 15;
  const int hh = l >> 2;
  for (int dl = tid >> 4; dl < ndst; dl += 64) {
    const int d = d0s + dl;
    const int beg = start2[dl];
    const int end = beg + cnt2[dl];
    const float sdv = sdl[dl * 4 + hh];

    float den[4] = {0.f, 0.f, 0.f, 0.f};
    float acc[8];
#pragma unroll
    for (int j = 0; j < 8; ++j) acc[j] = 0.f;

    int p = beg;
    for (; p + 3 < end; p += 4) {
      int s[4];
      float w[4];
      uint4 v[4];
#pragma unroll
      for (int q = 0; q < 4; ++q) s[q] = srcsort[p + q];
#pragma unroll
      for (int q = 0; q < 4; ++q) {
        float x = ssrc[(size_t)s[q] * 4 + hh] + sdv;
        x = x >= 0.f ? x : NEG_SLOPE * x;
        w[q] = __expf(x);
        v[q] = hp4[(size_t)s[q] * 16 + l];
      }
#pragma unroll
      for (int q = 0; q < 4; ++q) {
        den[q] += w[q];
        acc[0] = fmaf(w[q], bf2f(v[q].x & 0xffffu), acc[0]);
        acc[1] = fmaf(w[q], bf2f(v[q].x >> 16), acc[1]);
        acc[2] = fmaf(w[q], bf2f(v[q].y & 0xffffu), acc[2]);
        acc[3] = fmaf(w[q], bf2f(v[q].y >> 16), acc[3]);
        acc[4] = fmaf(w[q], bf2f(v[q].z & 0xffffu), acc[4]);
        acc[5] = fmaf(w[q], bf2f(v[q].z >> 16), acc[5]);
        acc[6] = fmaf(w[q], bf2f(v[q].w & 0xffffu), acc[6]);
        acc[7] = fmaf(w[q], bf2f(v[q].w >> 16), acc[7]);
      }
    }
    for (; p < end; ++p) {
      const int s0 = srcsort[p];
      float x = ssrc[(size_t)s0 * 4 + hh] + sdv;
      x = x >= 0.f ? x : NEG_SLOPE * x;
      const float w0 = __expf(x);
      const uint4 v0 = hp4[(size_t)s0 * 16 + l];
      den[0] += w0;
      acc[0] = fmaf(w0, bf2f(v0.x & 0xffffu), acc[0]);
      acc[1] = fmaf(w0, bf2f(v0.x >> 16), acc[1]);
      acc[2] = fmaf(w0, bf2f(v0.y & 0xffffu), acc[2]);
      acc[3] = fmaf(w0, bf2f(v0.y >> 16), acc[3]);
      acc[4] = fmaf(w0, bf2f(v0.z & 0xffffu), acc[4]);
      acc[5] = fmaf(w0, bf2f(v0.z >> 16), acc[5]);
      acc[6] = fmaf(w0, bf2f(v0.w & 0xffffu), acc[6]);
      acc[7] = fmaf(w0, bf2f(v0.w >> 16), acc[7]);
    }
    const float rden = 1.f / fmaxf((den[0] + den[1]) + (den[2] + den[3]), 1e-16f);
    float o[8];
#pragma unroll
    for (int j = 0; j < 8; ++j) {
      const float x = acc[j] * rden;
      o[j] = x > 0.f ? x : expm1f(x);
    }
    float* dst = &out[(size_t)d * 128 + l * 8];
    *(float4*)dst = make_float4(o[0], o[1], o[2], o[3]);
    *(float4*)(dst + 4) = make_float4(o[4], o[5], o[6], o[7]);
  }
}

extern "C" void kernel_launch(void* const* d_in, const int* in_sizes, int n_in,
                              void* d_out, int out_size, void* d_ws, size_t ws_size,
                              hipStream_t stream) {
  const float* h = (const float*)d_in[0];
  const int* ei = (const int*)d_in[1];
  const float* W = (const float*)d_in[2];
  const float* a = (const float*)d_in[3];
  float* out = (float*)d_out;
  const int N = in_sizes[0] / 128;
  const int E = in_sizes[1] / 2;
  const int NB2 = (N + 255) >> 8;          // coarse buckets (dst>>8), <=256
  const int NB1 = (E + 4095) / 4096;       // edge chunks
  const int NBG = max((N + 63) / 64, NB1); // fused gemm+bin grid

  char* ws = (char*)d_ws;
  uint4* gWf = (uint4*)ws;                                   // 4096 (64 KB)
  unsigned short* hp16 = (unsigned short*)(gWf + 4096);      // N*128 bf16
  uint2* gpairs = (uint2*)(hp16 + (size_t)N * 128);          // NB2*BCAP padded pairs
  float* ssrc = (float*)(gpairs + (size_t)NB2 * BCAP);       // N*4
  float* sdst = ssrc + (size_t)N * 4;                        // N*4
  int* bcur = (int*)(sdst + (size_t)N * 4);                  // NB2

  k_prep<<<8, 256, 0, stream>>>(W, gWf, bcur, NB2);
  k_gemm<<<NBG, 256, 0, stream>>>(h, gWf, a, ei, bcur, gpairs, hp16, ssrc, sdst,
                                  N, E, NB1, NB2);
  k_sortagg<<<NB2 * 2, 1024, 0, stream>>>(bcur, gpairs, ssrc, sdst,
                                          (const uint4*)hp16, out, N);
}

// Round 5
// 140.738 us; speedup vs baseline: 1.0527x; 1.0155x over previous
//
#include <hip/hip_runtime.h>

#define NEG_SLOPE 0.2f
#define BCAP 8192  // per-bucket slot capacity (mean 4096, sigma ~64 -> +64 sigma)

typedef __attribute__((ext_vector_type(8))) short short8;
typedef __attribute__((ext_vector_type(4))) float floatx4;

__device__ __forceinline__ unsigned f2bf(float x) {
  unsigned u = __float_as_uint(x);
  unsigned r = ((u >> 16) & 1u) + 0x7fffu;
  return (u + r) >> 16;
}
__device__ __forceinline__ float bf2f(unsigned hi16) {
  return __uint_as_float(hi16 << 16);
}

// ---------------- fused: edge binning + inline W->frag conversion + MFMA GEMM + attention dots ----------------
// k_prep is folded in: each block reads the L2-hot 64 KB W and converts to
// hi/lo bf16 fragments directly into LDS (same bytes as the old gWf load, no
// separate launch, no dependency bubble, no gWf round-trip).
__global__ __launch_bounds__(256) void k_gemm(const float* __restrict__ h,
                                              const float* __restrict__ W,
                                              const float* __restrict__ a,
                                              const int* __restrict__ ei,
                                              int* __restrict__ bcur,
                                              uint2* __restrict__ gpairs,
                                              unsigned short* __restrict__ hp16,
                                              float* __restrict__ ssrc,
                                              float* __restrict__ sdst,
                                              int N, int E, int NB1, int NB2) {
  __shared__ unsigned lds_u[16384];  // 64 KB multi-use: bin scratch -> B-frags -> epilogue
  const int tid = threadIdx.x;

  if (blockIdx.x < NB1) {  // block-uniform branch: barriers inside are legal
    uint2* stage = (uint2*)lds_u;              // 4096 pairs = 32 KB
    int* cnt = (int*)&lds_u[8192];
    int* start = (int*)&lds_u[8448];
    int* cur = (int*)&lds_u[8704];
    int* gbase = (int*)&lds_u[8960];
    int* scn = (int*)&lds_u[9216];
    const int e0 = blockIdx.x * 4096;
    for (int i = tid; i < NB2; i += 256) cnt[i] = 0;
    __syncthreads();
    int sarr[16], darr[16];
#pragma unroll
    for (int j = 0; j < 16; ++j) {
      int e = e0 + j * 256 + tid;
      if (e < E) {
        sarr[j] = ei[e];
        darr[j] = ei[E + e];
        atomicAdd(&cnt[darr[j] >> 8], 1);
      } else {
        darr[j] = -1;
      }
    }
    __syncthreads();
    int s = (tid < NB2) ? cnt[tid] : 0;
    scn[tid] = s;
    __syncthreads();
    for (int off = 1; off < 256; off <<= 1) {
      int t = (tid >= off) ? scn[tid - off] : 0;
      __syncthreads();
      scn[tid] += t;
      __syncthreads();
    }
    if (tid < NB2) {
      start[tid] = scn[tid] - s;
      cur[tid] = scn[tid] - s;
      gbase[tid] = s ? atomicAdd(&bcur[tid], s) : 0;  // reserve run in bucket
    }
    __syncthreads();
#pragma unroll
    for (int j = 0; j < 16; ++j) {
      if (darr[j] >= 0) {
        int b = darr[j] >> 8;
        int pos = atomicAdd(&cur[b], 1);
        stage[pos] = make_uint2((unsigned)sarr[j], (unsigned)darr[j]);
      }
    }
    __syncthreads();
    const int total = start[NB2 - 1] + cnt[NB2 - 1];
    for (int u = tid; u < total; u += 256) {
      uint2 pr = stage[u];
      int b = (int)(pr.y >> 8);
      gpairs[(size_t)b * BCAP + gbase[b] + (u - start[b])] = pr;
    }
    __syncthreads();  // lds_u scratch free
  }

  const int lane = tid & 63;
  const int wv = tid >> 6;
  const int quad = lane >> 4;
  const int l16 = lane & 15;

  // inline W -> hi/lo B-fragment conversion straight into LDS (was k_prep+gWf)
#pragma unroll
  for (int it = 0; it < 8; ++it) {
    const int u = it * 256 + tid;  // u in [0,2048)
    const int ln = u & 63;
    const int kc = (u >> 6) & 3;
    const int ct = u >> 8;
    const int n = ct * 16 + (ln & 15);
    const int kb = kc * 32 + (ln >> 4) * 8;
    const int head = n >> 5;
    const float* src = W + head * 4096 + (size_t)kb * 32 + (n & 31);
    unsigned hi[4], lo[4];
#pragma unroll
    for (int jj = 0; jj < 4; ++jj) {
      float w0 = src[(2 * jj) * 32];
      float w1 = src[(2 * jj + 1) * 32];
      unsigned h0 = f2bf(w0), h1 = f2bf(w1);
      unsigned l0 = f2bf(w0 - bf2f(h0)), l1 = f2bf(w1 - bf2f(h1));
      hi[jj] = h0 | (h1 << 16);
      lo[jj] = l0 | (l1 << 16);
    }
    *(uint4*)&lds_u[u * 4] = make_uint4(hi[0], hi[1], hi[2], hi[3]);
    *(uint4*)&lds_u[8192 + u * 4] = make_uint4(lo[0], lo[1], lo[2], lo[3]);
  }

  const int row0 = blockIdx.x * 64;
  const int r = row0 + wv * 16 + l16;
  short8 Ah[4], Al[4];
#pragma unroll
  for (int kc = 0; kc < 4; ++kc) {
    float v[8];
    if (r < N) {
      float4 fa = *(const float4*)&h[(size_t)r * 128 + kc * 32 + quad * 8];
      float4 fb = *(const float4*)&h[(size_t)r * 128 + kc * 32 + quad * 8 + 4];
      v[0] = fa.x; v[1] = fa.y; v[2] = fa.z; v[3] = fa.w;
      v[4] = fb.x; v[5] = fb.y; v[6] = fb.z; v[7] = fb.w;
    } else {
#pragma unroll
      for (int j = 0; j < 8; ++j) v[j] = 0.f;
    }
#pragma unroll
    for (int j = 0; j < 8; ++j) {
      unsigned hi = f2bf(v[j]);
      Ah[kc][j] = (short)hi;
      Al[kc][j] = (short)f2bf(v[j] - bf2f(hi));
    }
  }
  __syncthreads();

  floatx4 C[8];
#pragma unroll
  for (int ct = 0; ct < 8; ++ct) {
    floatx4 c = {0.f, 0.f, 0.f, 0.f};
#pragma unroll
    for (int kc = 0; kc < 4; ++kc) {
      int bidx = ((ct * 4 + kc) * 64 + lane) * 4;
      short8 Bh, Bl;
      *(uint4*)&Bh = *(const uint4*)&lds_u[bidx];
      *(uint4*)&Bl = *(const uint4*)&lds_u[8192 + bidx];
      c = __builtin_amdgcn_mfma_f32_16x16x32_bf16(Ah[kc], Bh, c, 0, 0, 0);
      c = __builtin_amdgcn_mfma_f32_16x16x32_bf16(Al[kc], Bh, c, 0, 0, 0);
      c = __builtin_amdgcn_mfma_f32_16x16x32_bf16(Ah[kc], Bl, c, 0, 0, 0);
    }
    C[ct] = c;
  }
  __syncthreads();

  float* epi = (float*)lds_u;
#pragma unroll
  for (int ct = 0; ct < 8; ++ct) {
#pragma unroll
    for (int reg = 0; reg < 4; ++reg) {
      int rr = wv * 16 + quad * 4 + reg;
      epi[rr * 132 + ct * 16 + l16] = C[ct][reg];
    }
  }
  __syncthreads();

  const int row_l = tid >> 2;
  const int hh = tid & 3;
  const int rg = row0 + row_l;
  if (rg < N) {
    const float* rowp = &epi[row_l * 132 + hh * 32];
    float ss = 0.f, sd = 0.f;
    unsigned pka[16];
#pragma unroll
    for (int e = 0; e < 8; ++e) {
      float4 c4 = *(const float4*)&rowp[e * 4];
      float4 as = *(const float4*)&a[hh * 64 + e * 4];
      float4 ad = *(const float4*)&a[hh * 64 + 32 + e * 4];
      ss += c4.x * as.x + c4.y * as.y + c4.z * as.z + c4.w * as.w;
      sd += c4.x * ad.x + c4.y * ad.y + c4.z * ad.z + c4.w * ad.w;
      pka[e * 2] = f2bf(c4.x) | (f2bf(c4.y) << 16);
      pka[e * 2 + 1] = f2bf(c4.z) | (f2bf(c4.w) << 16);
    }
    unsigned short* dst = &hp16[(size_t)rg * 128 + hh * 32];
    *(uint4*)(dst) = make_uint4(pka[0], pka[1], pka[2], pka[3]);
    *(uint4*)(dst + 8) = make_uint4(pka[4], pka[5], pka[6], pka[7]);
    *(uint4*)(dst + 16) = make_uint4(pka[8], pka[9], pka[10], pka[11]);
    *(uint4*)(dst + 24) = make_uint4(pka[12], pka[13], pka[14], pka[15]);
    ssrc[(size_t)rg * 4 + hh] = ss;
    sdst[(size_t)rg * 4 + hh] = sd;
  }
}

// ---------------- fused per-bucket counting sort (LDS-resident) + aggregation ----------------
// SPLIT=2 (unchanged from round 4): two blocks per bucket, each filters the
// bucket's pairs to its 128-dst half. Weights recomputed inline from
// L2-resident ssrc + LDS-preloaded sdst; no extra global arrays.
__global__ __launch_bounds__(1024) void k_sortagg(const int* __restrict__ bcur,
                                                  const uint2* __restrict__ gpairs,
                                                  const float* __restrict__ ssrc,
                                                  const float* __restrict__ sdst,
                                                  const uint4* __restrict__ hp4,
                                                  float* __restrict__ out, int N) {
  __shared__ int cnt2[128], start2[128], cur2[128], lds[128];
  __shared__ int srcsort[4096];   // 16 KB (sub-bucket mean 2048, +45 sigma)
  __shared__ float sdl[512];      // sdst[4] for this half-bucket's 128 dsts
  const int tid = threadIdx.x;
  const int b = blockIdx.x >> 1;          // bucket
  const int half = blockIdx.x & 1;        // which 128-dst half
  const size_t base = (size_t)b * BCAP;
  const int size = min(bcur[b], BCAP);    // defensive clamp
  const int d0s = (b << 8) + half * 128;  // sub-range base
  const int ndst = min(128, N - d0s);     // may be <=0 for tail half

  if (tid < 128) cnt2[tid] = 0;
  for (int i = tid; i < ndst * 4; i += 1024) sdl[i] = sdst[(size_t)d0s * 4 + i];
  __syncthreads();

  // stage bucket pairs in registers, filter to this half (BCAP = 8 * 1024)
  uint2 pr[8];
  int rel[8];
#pragma unroll
  for (int j = 0; j < 8; ++j) {
    const int u = tid + j * 1024;
    if (u < size) pr[j] = gpairs[base + u];
    else pr[j].y = 0xffffffffu;
    rel[j] = (int)pr[j].y - d0s;
    if ((unsigned)rel[j] >= 128u) rel[j] = -1;
  }
#pragma unroll
  for (int j = 0; j < 8; ++j)
    if (rel[j] >= 0) atomicAdd(&cnt2[rel[j]], 1);
  __syncthreads();

  // prefix scan over 128 counters (barriers uniform across the 1024 threads)
  if (tid < 128) lds[tid] = cnt2[tid];
  __syncthreads();
  for (int off = 1; off < 128; off <<= 1) {
    const int t = (tid < 128 && tid >= off) ? lds[tid - off] : 0;
    __syncthreads();
    if (tid < 128) lds[tid] += t;
    __syncthreads();
  }
  if (tid < 128) {
    start2[tid] = lds[tid] - cnt2[tid];
    cur2[tid] = lds[tid] - cnt2[tid];
  }
  __syncthreads();

  // scatter src ids into sorted LDS positions
#pragma unroll
  for (int j = 0; j < 8; ++j) {
    if (rel[j] >= 0) {
      const int pos = atomicAdd(&cur2[rel[j]], 1);
      srcsort[pos] = (int)pr[j].x;
    }
  }
  __syncthreads();

  // aggregation: 16 lanes per dst, 64 dsts in flight, <=2 rounds
  const int l = tid & 15;
  const int hh = l >> 2;
  for (int dl = tid >> 4; dl < ndst; dl += 64) {
    const int d = d0s + dl;
    const int beg = start2[dl];
    const int end = beg + cnt2[dl];
    const float sdv = sdl[dl * 4 + hh];

    float den[4] = {0.f, 0.f, 0.f, 0.f};
    float acc[8];
#pragma unroll
    for (int j = 0; j < 8; ++j) acc[j] = 0.f;

    int p = beg;
    for (; p + 3 < end; p += 4) {
      int s[4];
      float w[4];
      uint4 v[4];
#pragma unroll
      for (int q = 0; q < 4; ++q) s[q] = srcsort[p + q];
#pragma unroll
      for (int q = 0; q < 4; ++q) {
        float x = ssrc[(size_t)s[q] * 4 + hh] + sdv;
        x = x >= 0.f ? x : NEG_SLOPE * x;
        w[q] = __expf(x);
        v[q] = hp4[(size_t)s[q] * 16 + l];
      }
#pragma unroll
      for (int q = 0; q < 4; ++q) {
        den[q] += w[q];
        acc[0] = fmaf(w[q], bf2f(v[q].x & 0xffffu), acc[0]);
        acc[1] = fmaf(w[q], bf2f(v[q].x >> 16), acc[1]);
        acc[2] = fmaf(w[q], bf2f(v[q].y & 0xffffu), acc[2]);
        acc[3] = fmaf(w[q], bf2f(v[q].y >> 16), acc[3]);
        acc[4] = fmaf(w[q], bf2f(v[q].z & 0xffffu), acc[4]);
        acc[5] = fmaf(w[q], bf2f(v[q].z >> 16), acc[5]);
        acc[6] = fmaf(w[q], bf2f(v[q].w & 0xffffu), acc[6]);
        acc[7] = fmaf(w[q], bf2f(v[q].w >> 16), acc[7]);
      }
    }
    for (; p < end; ++p) {
      const int s0 = srcsort[p];
      float x = ssrc[(size_t)s0 * 4 + hh] + sdv;
      x = x >= 0.f ? x : NEG_SLOPE * x;
      const float w0 = __expf(x);
      const uint4 v0 = hp4[(size_t)s0 * 16 + l];
      den[0] += w0;
      acc[0] = fmaf(w0, bf2f(v0.x & 0xffffu), acc[0]);
      acc[1] = fmaf(w0, bf2f(v0.x >> 16), acc[1]);
      acc[2] = fmaf(w0, bf2f(v0.y & 0xffffu), acc[2]);
      acc[3] = fmaf(w0, bf2f(v0.y >> 16), acc[3]);
      acc[4] = fmaf(w0, bf2f(v0.z & 0xffffu), acc[4]);
      acc[5] = fmaf(w0, bf2f(v0.z >> 16), acc[5]);
      acc[6] = fmaf(w0, bf2f(v0.w & 0xffffu), acc[6]);
      acc[7] = fmaf(w0, bf2f(v0.w >> 16), acc[7]);
    }
    const float rden = 1.f / fmaxf((den[0] + den[1]) + (den[2] + den[3]), 1e-16f);
    float o[8];
#pragma unroll
    for (int j = 0; j < 8; ++j) {
      const float x = acc[j] * rden;
      o[j] = x > 0.f ? x : expm1f(x);
    }
    float* dst = &out[(size_t)d * 128 + l * 8];
    *(float4*)dst = make_float4(o[0], o[1], o[2], o[3]);
    *(float4*)(dst + 4) = make_float4(o[4], o[5], o[6], o[7]);
  }
}

extern "C" void kernel_launch(void* const* d_in, const int* in_sizes, int n_in,
                              void* d_out, int out_size, void* d_ws, size_t ws_size,
                              hipStream_t stream) {
  const float* h = (const float*)d_in[0];
  const int* ei = (const int*)d_in[1];
  const float* W = (const float*)d_in[2];
  const float* a = (const float*)d_in[3];
  float* out = (float*)d_out;
  const int N = in_sizes[0] / 128;
  const int E = in_sizes[1] / 2;
  const int NB2 = (N + 255) >> 8;          // coarse buckets (dst>>8), <=256
  const int NB1 = (E + 4095) / 4096;       // edge chunks
  const int NBG = max((N + 63) / 64, NB1); // fused gemm+bin grid

  char* ws = (char*)d_ws;
  unsigned short* hp16 = (unsigned short*)ws;                // N*128 bf16
  uint2* gpairs = (uint2*)(hp16 + (size_t)N * 128);          // NB2*BCAP padded pairs
  float* ssrc = (float*)(gpairs + (size_t)NB2 * BCAP);       // N*4
  float* sdst = ssrc + (size_t)N * 4;                        // N*4
  int* bcur = (int*)(sdst + (size_t)N * 4);                  // NB2

  hipMemsetAsync(bcur, 0, NB2 * sizeof(int), stream);        // graph-safe tiny fill
  k_gemm<<<NBG, 256, 0, stream>>>(h, W, a, ei, bcur, gpairs, hp16, ssrc, sdst,
                                  N, E, NB1, NB2);
  k_sortagg<<<NB2 * 2, 1024, 0, stream>>>(bcur, gpairs, ssrc, sdst,
                                          (const uint4*)hp16, out, N);
}